// Round 1
// baseline (305.458 us; speedup 1.0000x reference)
//
#include <hip/hip_runtime.h>
#include <hip/hip_bf16.h>
#include <math.h>

#define IN_F 512
#define OUT_F 256
#define ALPHA 0.2f
#define CAP 2048   // max supported row degree (E/N ~ 32, Poisson tail << 2048)

// ---------------- GEMM: h[m,n] = sum_k x[m,k] * W[n,k] + b[n] ----------------
__global__ __launch_bounds__(256) void gemm_h(const float* __restrict__ x,
                                              const float* __restrict__ W,
                                              const float* __restrict__ b,
                                              float* __restrict__ h, int N_) {
  const int BK = 32;
  __shared__ float sA[64][BK + 1];
  __shared__ float sB[64][BK + 1];
  int bm = blockIdx.x * 64;
  int bn = blockIdx.y * 64;
  int tid = threadIdx.x;
  int tr = tid / 16, tc = tid % 16;   // 16x16 threads, each 4x4 outputs
  float acc[4][4] = {};
  for (int k0 = 0; k0 < IN_F; k0 += BK) {
    for (int i = tid; i < 64 * BK; i += 256) {
      int r = i / BK, c = i % BK;
      int gm = bm + r;
      sA[r][c] = (gm < N_) ? x[(size_t)gm * IN_F + k0 + c] : 0.f;
    }
    for (int i = tid; i < 64 * BK; i += 256) {
      int r = i / BK, c = i % BK;
      sB[r][c] = W[(size_t)(bn + r) * IN_F + k0 + c];  // bn+r < 256 always
    }
    __syncthreads();
    for (int kk = 0; kk < BK; ++kk) {
      float av[4], bv[4];
#pragma unroll
      for (int i = 0; i < 4; ++i) av[i] = sA[tr * 4 + i][kk];
#pragma unroll
      for (int j = 0; j < 4; ++j) bv[j] = sB[tc * 4 + j][kk];
#pragma unroll
      for (int i = 0; i < 4; ++i)
#pragma unroll
        for (int j = 0; j < 4; ++j) acc[i][j] += av[i] * bv[j];
    }
    __syncthreads();
  }
#pragma unroll
  for (int i = 0; i < 4; ++i) {
    int gm = bm + tr * 4 + i;
    if (gm >= N_) continue;
#pragma unroll
    for (int j = 0; j < 4; ++j) {
      int gn = bn + tc * 4 + j;
      h[(size_t)gm * OUT_F + gn] = acc[i][j] + b[gn];
    }
  }
}

// ---------------- per-node attention half-scores: s1 = h.a[:256], s2 = h.a[256:] ----------------
__global__ __launch_bounds__(256) void score_nodes(const float* __restrict__ h,
                                                   const float* __restrict__ a,
                                                   float* __restrict__ s1,
                                                   float* __restrict__ s2, int N_) {
  int node = blockIdx.x * 4 + (threadIdx.x >> 6);
  int lane = threadIdx.x & 63;
  if (node >= N_) return;
  const float* hr = h + (size_t)node * OUT_F;
  float v1 = 0.f, v2 = 0.f;
#pragma unroll
  for (int f = lane; f < OUT_F; f += 64) {
    float hv = hr[f];
    v1 += hv * a[f];
    v2 += hv * a[OUT_F + f];
  }
#pragma unroll
  for (int off = 32; off; off >>= 1) {
    v1 += __shfl_down(v1, off);
    v2 += __shfl_down(v2, off);
  }
  if (lane == 0) { s1[node] = v1; s2[node] = v2; }
}

// ---------------- column sum of h (fallback for empty rows: uniform softmax -> mean) ----------------
__global__ __launch_bounds__(256) void colsum(const float* __restrict__ h,
                                              float* __restrict__ hsum, int N_) {
  int f = threadIdx.x;
  float acc = 0.f;
  for (int r = blockIdx.x; r < N_; r += gridDim.x) acc += h[(size_t)r * OUT_F + f];
  atomicAdd(&hsum[f], acc);
}

// ---------------- CSR build ----------------
__global__ void count_deg(const int* __restrict__ edges, int* __restrict__ deg, int E_) {
  int e = blockIdx.x * blockDim.x + threadIdx.x;
  if (e < E_) atomicAdd(&deg[edges[e]], 1);  // edges[0][e] = src
}

__global__ __launch_bounds__(1024) void scan_deg(const int* __restrict__ deg,
                                                 int* __restrict__ offs, int N_) {
  __shared__ int s[1024];
  int tid = threadIdx.x;
  int chunk = (N_ + 1023) / 1024;
  int base = tid * chunk;
  int mysum = 0;
  for (int j = 0; j < chunk; ++j) {
    int idx = base + j;
    mysum += (idx < N_) ? deg[idx] : 0;
  }
  s[tid] = mysum;
  __syncthreads();
  for (int offset = 1; offset < 1024; offset <<= 1) {
    int t = (tid >= offset) ? s[tid - offset] : 0;
    __syncthreads();
    s[tid] += t;
    __syncthreads();
  }
  int run = s[tid] - mysum;  // exclusive prefix of this chunk
  for (int j = 0; j < chunk; ++j) {
    int idx = base + j;
    if (idx < N_) { offs[idx] = run; run += deg[idx]; }
  }
  if (tid == 1023) offs[N_] = s[1023];
}

__global__ void fill_csr(const int* __restrict__ edges, const int* __restrict__ offs,
                         int* __restrict__ cursor, int* __restrict__ csr, int E_) {
  int e = blockIdx.x * blockDim.x + threadIdx.x;
  if (e >= E_) return;
  int srcv = edges[e];
  int tgtv = edges[E_ + e];
  int pos = offs[srcv] + atomicAdd(&cursor[srcv], 1);
  csr[pos] = tgtv;
}

// ---------------- per-row: merge duplicates, softmax, weighted gather ----------------
__global__ __launch_bounds__(256) void row_softmax(const float* __restrict__ h,
                                                   const float* __restrict__ s1,
                                                   const float* __restrict__ s2,
                                                   const int* __restrict__ offs,
                                                   const int* __restrict__ csr,
                                                   const float* __restrict__ hsum,
                                                   float* __restrict__ out, int N_) {
  int row = blockIdx.x;
  int tid = threadIdx.x;  // 0..255 == feature index
  int o0 = offs[row];
  int deg = offs[row + 1] - o0;
  if (deg > CAP) deg = CAP;  // unreachable with this data; safety clamp

  __shared__ int s_tgt[CAP];
  __shared__ float s_w[CAP];

  if (deg == 0) {
    // whole adj row == NEG_BIG -> uniform softmax -> mean of h
    out[(size_t)row * OUT_F + tid] = hsum[tid] * (1.0f / (float)N_);
    return;
  }
  for (int p = tid; p < deg; p += 256) s_tgt[p] = csr[o0 + p];
  __syncthreads();

  float s1i = s1[row];
  for (int p = tid; p < deg; p += 256) {
    int t = s_tgt[p];
    int first = p, cnt = 0;
    for (int q = 0; q < deg; ++q) {
      int tq = s_tgt[q];
      if (tq == t) { ++cnt; if (q < first) first = q; }
    }
    float v;
    if (first == p) {
      // duplicate edges have IDENTICAL scores (score depends only on (src,tgt)):
      // scatter-add sum == multiplicity * leaky_relu(s1+s2)
      float s = s1i + s2[t];
      s = (s > 0.f) ? s : ALPHA * s;
      v = (float)cnt * s;
      if (v == 0.f) v = -INFINITY;  // adj==0 -> NEG_BIG -> excluded
    } else {
      v = -INFINITY;  // non-leader duplicate slot
    }
    s_w[p] = v;
  }
  __syncthreads();

  float m = -INFINITY;
  for (int q = 0; q < deg; ++q) m = fmaxf(m, s_w[q]);  // LDS broadcast reads

  if (m == -INFINITY) {  // all merged values were exactly 0 -> uniform row
    out[(size_t)row * OUT_F + tid] = hsum[tid] * (1.0f / (float)N_);
    return;
  }

  for (int p = tid; p < deg; p += 256) {
    float v = s_w[p];
    s_w[p] = (v == -INFINITY) ? 0.f : expf(v - m);
  }
  __syncthreads();

  float denom = 0.f;
  for (int q = 0; q < deg; ++q) denom += s_w[q];

  float acc = 0.f;
  for (int p = 0; p < deg; ++p) {
    float wv = s_w[p];
    if (wv != 0.f) acc += wv * h[(size_t)s_tgt[p] * OUT_F + tid];
  }
  out[(size_t)row * OUT_F + tid] = acc * (1.0f / denom);
}

extern "C" void kernel_launch(void* const* d_in, const int* in_sizes, int n_in,
                              void* d_out, int out_size, void* d_ws, size_t ws_size,
                              hipStream_t stream) {
  const float* x = (const float*)d_in[0];
  const float* W = (const float*)d_in[1];
  const float* b = (const float*)d_in[2];
  const float* a = (const float*)d_in[3];
  const int* edges = (const int*)d_in[4];
  float* out = (float*)d_out;

  int N_ = in_sizes[0] / IN_F;   // 10000
  int E_ = in_sizes[4] / 2;      // 320000

  char* ws = (char*)d_ws;
  size_t off = 0;
  auto alloc = [&](size_t bytes) {
    char* p = ws + off;
    off = (off + bytes + 255) & ~(size_t)255;
    return p;
  };
  float* h      = (float*)alloc((size_t)N_ * OUT_F * sizeof(float));
  float* s1     = (float*)alloc((size_t)N_ * sizeof(float));
  float* s2     = (float*)alloc((size_t)N_ * sizeof(float));
  float* hsum   = (float*)alloc(OUT_F * sizeof(float));
  int*   deg    = (int*)alloc((size_t)N_ * sizeof(int));
  int*   offs   = (int*)alloc((size_t)(N_ + 1) * sizeof(int));
  int*   cursor = (int*)alloc((size_t)N_ * sizeof(int));
  int*   csr    = (int*)alloc((size_t)E_ * sizeof(int));

  // zero the accumulated buffers every call (ws is poisoned once, never restored)
  hipMemsetAsync(hsum, 0, OUT_F * sizeof(float), stream);
  hipMemsetAsync(deg, 0, (size_t)N_ * sizeof(int), stream);
  hipMemsetAsync(cursor, 0, (size_t)N_ * sizeof(int), stream);

  dim3 ggrid((N_ + 63) / 64, OUT_F / 64);
  gemm_h<<<ggrid, 256, 0, stream>>>(x, W, b, h, N_);
  score_nodes<<<(N_ + 3) / 4, 256, 0, stream>>>(h, a, s1, s2, N_);
  colsum<<<64, 256, 0, stream>>>(h, hsum, N_);
  count_deg<<<(E_ + 255) / 256, 256, 0, stream>>>(edges, deg, E_);
  scan_deg<<<1, 1024, 0, stream>>>(deg, offs, N_);
  fill_csr<<<(E_ + 255) / 256, 256, 0, stream>>>(edges, offs, cursor, csr, E_);
  row_softmax<<<N_, 256, 0, stream>>>(h, s1, s2, offs, csr, hsum, out, N_);
}

// Round 2
// 221.366 us; speedup vs baseline: 1.3799x; 1.3799x over previous
//
#include <hip/hip_runtime.h>
#include <hip/hip_bf16.h>
#include <math.h>

#define IN_F 512
#define OUT_F 256
#define ALPHA 0.2f
#define CAP 2048   // max supported row degree (E/N ~ 32, Poisson tail << 2048)

typedef __attribute__((ext_vector_type(8))) short bf16x8;
typedef __attribute__((ext_vector_type(4))) float f32x4;

static __device__ __forceinline__ unsigned short f2bf(float f) {
  unsigned int u = __builtin_bit_cast(unsigned int, f);
  unsigned int r = (u + 0x7FFFu + ((u >> 16) & 1u)) >> 16;  // round-to-nearest-even
  return (unsigned short)r;
}

// ---------------- GEMM (bf16 MFMA): h[m,n] = sum_k x[m,k]*W[n,k] + b[n] ----------------
// x: [N,512] fp32 (A, row-major M x K). W: [256,512] fp32 (= B^T, i.e. [N_out, K]).
// Tile 64x64, BK=64, 4 waves each computing a 32x32 quadrant via 2x2 16x16x32 MFMAs.
__global__ __launch_bounds__(256) void gemm_h_mfma(const float* __restrict__ x,
                                                   const float* __restrict__ W,
                                                   const float* __restrict__ bias,
                                                   float* __restrict__ h, int N_) {
  // padded row stride 72 bf16 (=144B, 16B-aligned; rows 8 apart alias banks 2-way = free)
  __shared__ unsigned short lA[64][72];
  __shared__ unsigned short lB[64][72];
  const int bm = blockIdx.x * 64;
  const int bn = blockIdx.y * 64;
  const int tid = threadIdx.x;
  const int wave = tid >> 6, lane = tid & 63;
  const int wr = wave >> 1, wc = wave & 1;       // 32x32 quadrant coords
  const int lr = lane & 15, lk = lane >> 4;      // fragment lane decomposition

  f32x4 acc[2][2] = {};

  for (int k0 = 0; k0 < IN_F; k0 += 64) {
    // ---- stage 64x64 fp32 -> bf16 LDS (A and B), 4 float4 per thread each ----
#pragma unroll
    for (int r = 0; r < 4; ++r) {
      int idx = tid + r * 256;          // 0..1023
      int row = idx >> 4, c4 = idx & 15;
      int gm = bm + row;
      float4 va = (gm < N_) ? *(const float4*)&x[(size_t)gm * IN_F + k0 + c4 * 4]
                            : make_float4(0.f, 0.f, 0.f, 0.f);
      ushort4 oa;
      oa.x = f2bf(va.x); oa.y = f2bf(va.y); oa.z = f2bf(va.z); oa.w = f2bf(va.w);
      *(ushort4*)&lA[row][c4 * 4] = oa;
      float4 vb = *(const float4*)&W[(size_t)(bn + row) * IN_F + k0 + c4 * 4];  // bn+row < 256 always
      ushort4 ob;
      ob.x = f2bf(vb.x); ob.y = f2bf(vb.y); ob.z = f2bf(vb.z); ob.w = f2bf(vb.w);
      *(ushort4*)&lB[row][c4 * 4] = ob;
    }
    __syncthreads();

    // ---- 2 k-subtiles of 32, 2x2 fragments each ----
#pragma unroll
    for (int kk = 0; kk < 64; kk += 32) {
      bf16x8 af[2], bfr[2];
#pragma unroll
      for (int fm = 0; fm < 2; ++fm)
        af[fm] = *(const bf16x8*)&lA[wr * 32 + fm * 16 + lr][kk + lk * 8];
#pragma unroll
      for (int fn = 0; fn < 2; ++fn)
        bfr[fn] = *(const bf16x8*)&lB[wc * 32 + fn * 16 + lr][kk + lk * 8];
#pragma unroll
      for (int fm = 0; fm < 2; ++fm)
#pragma unroll
        for (int fn = 0; fn < 2; ++fn)
          acc[fm][fn] = __builtin_amdgcn_mfma_f32_16x16x32_bf16(af[fm], bfr[fn],
                                                                acc[fm][fn], 0, 0, 0);
    }
    __syncthreads();
  }

  // ---- epilogue: C/D layout col=lane&15, row=(lane>>4)*4+reg ----
#pragma unroll
  for (int fm = 0; fm < 2; ++fm) {
#pragma unroll
    for (int i = 0; i < 4; ++i) {
      int gr = bm + wr * 32 + fm * 16 + lk * 4 + i;
      if (gr >= N_) continue;
#pragma unroll
      for (int fn = 0; fn < 2; ++fn) {
        int gc = bn + wc * 32 + fn * 16 + lr;
        h[(size_t)gr * OUT_F + gc] = acc[fm][fn][i] + bias[gc];
      }
    }
  }
}

// ---------------- per-node attention half-scores: s1 = h.a[:256], s2 = h.a[256:] ----------------
__global__ __launch_bounds__(256) void score_nodes(const float* __restrict__ h,
                                                   const float* __restrict__ a,
                                                   float* __restrict__ s1,
                                                   float* __restrict__ s2, int N_) {
  int node = blockIdx.x * 4 + (threadIdx.x >> 6);
  int lane = threadIdx.x & 63;
  if (node >= N_) return;
  const float* hr = h + (size_t)node * OUT_F;
  float v1 = 0.f, v2 = 0.f;
#pragma unroll
  for (int f = lane; f < OUT_F; f += 64) {
    float hv = hr[f];
    v1 += hv * a[f];
    v2 += hv * a[OUT_F + f];
  }
#pragma unroll
  for (int off = 32; off; off >>= 1) {
    v1 += __shfl_down(v1, off);
    v2 += __shfl_down(v2, off);
  }
  if (lane == 0) { s1[node] = v1; s2[node] = v2; }
}

// ---------------- column sum of h (fallback for empty rows: uniform softmax -> mean) ----------------
__global__ __launch_bounds__(256) void colsum(const float* __restrict__ h,
                                              float* __restrict__ hsum, int N_) {
  int f = threadIdx.x;
  float acc = 0.f;
  for (int r = blockIdx.x; r < N_; r += gridDim.x) acc += h[(size_t)r * OUT_F + f];
  atomicAdd(&hsum[f], acc);
}

// ---------------- CSR build ----------------
__global__ void count_deg(const int* __restrict__ edges, int* __restrict__ deg, int E_) {
  int e = blockIdx.x * blockDim.x + threadIdx.x;
  if (e < E_) atomicAdd(&deg[edges[e]], 1);  // edges[0][e] = src
}

__global__ __launch_bounds__(1024) void scan_deg(const int* __restrict__ deg,
                                                 int* __restrict__ offs, int N_) {
  __shared__ int s[1024];
  int tid = threadIdx.x;
  int chunk = (N_ + 1023) / 1024;
  int base = tid * chunk;
  int mysum = 0;
  for (int j = 0; j < chunk; ++j) {
    int idx = base + j;
    mysum += (idx < N_) ? deg[idx] : 0;
  }
  s[tid] = mysum;
  __syncthreads();
  for (int offset = 1; offset < 1024; offset <<= 1) {
    int t = (tid >= offset) ? s[tid - offset] : 0;
    __syncthreads();
    s[tid] += t;
    __syncthreads();
  }
  int run = s[tid] - mysum;  // exclusive prefix of this chunk
  for (int j = 0; j < chunk; ++j) {
    int idx = base + j;
    if (idx < N_) { offs[idx] = run; run += deg[idx]; }
  }
  if (tid == 1023) offs[N_] = s[1023];
}

__global__ void fill_csr(const int* __restrict__ edges, const int* __restrict__ offs,
                         int* __restrict__ cursor, int* __restrict__ csr, int E_) {
  int e = blockIdx.x * blockDim.x + threadIdx.x;
  if (e >= E_) return;
  int srcv = edges[e];
  int tgtv = edges[E_ + e];
  int pos = offs[srcv] + atomicAdd(&cursor[srcv], 1);
  csr[pos] = tgtv;
}

// ---------------- per-row: merge duplicates, softmax, weighted gather ----------------
__global__ __launch_bounds__(256) void row_softmax(const float* __restrict__ h,
                                                   const float* __restrict__ s1,
                                                   const float* __restrict__ s2,
                                                   const int* __restrict__ offs,
                                                   const int* __restrict__ csr,
                                                   const float* __restrict__ hsum,
                                                   float* __restrict__ out, int N_) {
  int row = blockIdx.x;
  int tid = threadIdx.x;  // 0..255 == feature index
  int o0 = offs[row];
  int deg = offs[row + 1] - o0;
  if (deg > CAP) deg = CAP;  // unreachable with this data; safety clamp

  __shared__ int s_tgt[CAP];
  __shared__ float s_w[CAP];

  if (deg == 0) {
    // whole adj row == NEG_BIG -> uniform softmax -> mean of h
    out[(size_t)row * OUT_F + tid] = hsum[tid] * (1.0f / (float)N_);
    return;
  }
  for (int p = tid; p < deg; p += 256) s_tgt[p] = csr[o0 + p];
  __syncthreads();

  float s1i = s1[row];
  for (int p = tid; p < deg; p += 256) {
    int t = s_tgt[p];
    int first = p, cnt = 0;
    for (int q = 0; q < deg; ++q) {
      int tq = s_tgt[q];
      if (tq == t) { ++cnt; if (q < first) first = q; }
    }
    float v;
    if (first == p) {
      // duplicate edges have IDENTICAL scores (score depends only on (src,tgt)):
      // scatter-add sum == multiplicity * leaky_relu(s1+s2)
      float s = s1i + s2[t];
      s = (s > 0.f) ? s : ALPHA * s;
      v = (float)cnt * s;
      if (v == 0.f) v = -INFINITY;  // adj==0 -> NEG_BIG -> excluded
    } else {
      v = -INFINITY;  // non-leader duplicate slot
    }
    s_w[p] = v;
  }
  __syncthreads();

  float m = -INFINITY;
  for (int q = 0; q < deg; ++q) m = fmaxf(m, s_w[q]);  // LDS broadcast reads

  if (m == -INFINITY) {  // all merged values were exactly 0 -> uniform row
    out[(size_t)row * OUT_F + tid] = hsum[tid] * (1.0f / (float)N_);
    return;
  }

  for (int p = tid; p < deg; p += 256) {
    float v = s_w[p];
    s_w[p] = (v == -INFINITY) ? 0.f : expf(v - m);
  }
  __syncthreads();

  float denom = 0.f;
  for (int q = 0; q < deg; ++q) denom += s_w[q];

  float acc = 0.f;
  for (int p = 0; p < deg; ++p) {
    float wv = s_w[p];
    if (wv != 0.f) acc += wv * h[(size_t)s_tgt[p] * OUT_F + tid];
  }
  out[(size_t)row * OUT_F + tid] = acc * (1.0f / denom);
}

extern "C" void kernel_launch(void* const* d_in, const int* in_sizes, int n_in,
                              void* d_out, int out_size, void* d_ws, size_t ws_size,
                              hipStream_t stream) {
  const float* x = (const float*)d_in[0];
  const float* W = (const float*)d_in[1];
  const float* b = (const float*)d_in[2];
  const float* a = (const float*)d_in[3];
  const int* edges = (const int*)d_in[4];
  float* out = (float*)d_out;

  int N_ = in_sizes[0] / IN_F;   // 10000
  int E_ = in_sizes[4] / 2;      // 320000

  char* ws = (char*)d_ws;
  size_t off = 0;
  auto alloc = [&](size_t bytes) {
    char* p = ws + off;
    off = (off + bytes + 255) & ~(size_t)255;
    return p;
  };
  float* h      = (float*)alloc((size_t)N_ * OUT_F * sizeof(float));
  float* s1     = (float*)alloc((size_t)N_ * sizeof(float));
  float* s2     = (float*)alloc((size_t)N_ * sizeof(float));
  float* hsum   = (float*)alloc(OUT_F * sizeof(float));
  int*   deg    = (int*)alloc((size_t)N_ * sizeof(int));
  int*   offs   = (int*)alloc((size_t)(N_ + 1) * sizeof(int));
  int*   cursor = (int*)alloc((size_t)N_ * sizeof(int));
  int*   csr    = (int*)alloc((size_t)E_ * sizeof(int));

  // zero the accumulated buffers every call (ws is poisoned once, never restored)
  hipMemsetAsync(hsum, 0, OUT_F * sizeof(float), stream);
  hipMemsetAsync(deg, 0, (size_t)N_ * sizeof(int), stream);
  hipMemsetAsync(cursor, 0, (size_t)N_ * sizeof(int), stream);

  dim3 ggrid((N_ + 63) / 64, OUT_F / 64);
  gemm_h_mfma<<<ggrid, 256, 0, stream>>>(x, W, b, h, N_);
  score_nodes<<<(N_ + 3) / 4, 256, 0, stream>>>(h, a, s1, s2, N_);
  colsum<<<64, 256, 0, stream>>>(h, hsum, N_);
  count_deg<<<(E_ + 255) / 256, 256, 0, stream>>>(edges, deg, E_);
  scan_deg<<<1, 1024, 0, stream>>>(deg, offs, N_);
  fill_csr<<<(E_ + 255) / 256, 256, 0, stream>>>(edges, offs, cursor, csr, E_);
  row_softmax<<<N_, 256, 0, stream>>>(h, s1, s2, offs, csr, hsum, out, N_);
}

// Round 3
// 171.448 us; speedup vs baseline: 1.7816x; 1.2912x over previous
//
#include <hip/hip_runtime.h>
#include <hip/hip_bf16.h>
#include <math.h>

#define IN_F 512
#define OUT_F 256
#define ALPHA 0.2f
#define CAP 512   // max row degree; deg ~ Poisson(32), P(deg>512) ~ 1e-300

typedef __attribute__((ext_vector_type(8))) short bf16x8;
typedef __attribute__((ext_vector_type(4))) float f32x4;

static __device__ __forceinline__ unsigned short f2bf(float f) {
  unsigned int u = __builtin_bit_cast(unsigned int, f);
  unsigned int r = (u + 0x7FFFu + ((u >> 16) & 1u)) >> 16;  // round-to-nearest-even
  return (unsigned short)r;
}

// ---------------- GEMM (bf16 MFMA): h[m,n] = sum_k x[m,k]*W[n,k] + b[n] ----------------
__global__ __launch_bounds__(256) void gemm_h_mfma(const float* __restrict__ x,
                                                   const float* __restrict__ W,
                                                   const float* __restrict__ bias,
                                                   float* __restrict__ h, int N_) {
  __shared__ unsigned short lA[64][72];
  __shared__ unsigned short lB[64][72];
  const int bm = blockIdx.x * 64;
  const int bn = blockIdx.y * 64;
  const int tid = threadIdx.x;
  const int wave = tid >> 6, lane = tid & 63;
  const int wr = wave >> 1, wc = wave & 1;
  const int lr = lane & 15, lk = lane >> 4;

  f32x4 acc[2][2] = {};

  for (int k0 = 0; k0 < IN_F; k0 += 64) {
#pragma unroll
    for (int r = 0; r < 4; ++r) {
      int idx = tid + r * 256;
      int row = idx >> 4, c4 = idx & 15;
      int gm = bm + row;
      float4 va = (gm < N_) ? *(const float4*)&x[(size_t)gm * IN_F + k0 + c4 * 4]
                            : make_float4(0.f, 0.f, 0.f, 0.f);
      ushort4 oa;
      oa.x = f2bf(va.x); oa.y = f2bf(va.y); oa.z = f2bf(va.z); oa.w = f2bf(va.w);
      *(ushort4*)&lA[row][c4 * 4] = oa;
      float4 vb = *(const float4*)&W[(size_t)(bn + row) * IN_F + k0 + c4 * 4];
      ushort4 ob;
      ob.x = f2bf(vb.x); ob.y = f2bf(vb.y); ob.z = f2bf(vb.z); ob.w = f2bf(vb.w);
      *(ushort4*)&lB[row][c4 * 4] = ob;
    }
    __syncthreads();
#pragma unroll
    for (int kk = 0; kk < 64; kk += 32) {
      bf16x8 af[2], bfr[2];
#pragma unroll
      for (int fm = 0; fm < 2; ++fm)
        af[fm] = *(const bf16x8*)&lA[wr * 32 + fm * 16 + lr][kk + lk * 8];
#pragma unroll
      for (int fn = 0; fn < 2; ++fn)
        bfr[fn] = *(const bf16x8*)&lB[wc * 32 + fn * 16 + lr][kk + lk * 8];
#pragma unroll
      for (int fm = 0; fm < 2; ++fm)
#pragma unroll
        for (int fn = 0; fn < 2; ++fn)
          acc[fm][fn] = __builtin_amdgcn_mfma_f32_16x16x32_bf16(af[fm], bfr[fn],
                                                                acc[fm][fn], 0, 0, 0);
    }
    __syncthreads();
  }

#pragma unroll
  for (int fm = 0; fm < 2; ++fm) {
#pragma unroll
    for (int i = 0; i < 4; ++i) {
      int gr = bm + wr * 32 + fm * 16 + lk * 4 + i;
      if (gr >= N_) continue;
#pragma unroll
      for (int fn = 0; fn < 2; ++fn) {
        int gc = bn + wc * 32 + fn * 16 + lr;
        h[(size_t)gr * OUT_F + gc] = acc[fm][fn][i] + bias[gc];
      }
    }
  }
}

// ---------------- per-node attention half-scores ----------------
__global__ __launch_bounds__(256) void score_nodes(const float* __restrict__ h,
                                                   const float* __restrict__ a,
                                                   float* __restrict__ s1,
                                                   float* __restrict__ s2, int N_) {
  int node = blockIdx.x * 4 + (threadIdx.x >> 6);
  int lane = threadIdx.x & 63;
  if (node >= N_) return;
  const float* hr = h + (size_t)node * OUT_F;
  float v1 = 0.f, v2 = 0.f;
#pragma unroll
  for (int f = lane; f < OUT_F; f += 64) {
    float hv = hr[f];
    v1 += hv * a[f];
    v2 += hv * a[OUT_F + f];
  }
#pragma unroll
  for (int off = 32; off; off >>= 1) {
    v1 += __shfl_down(v1, off);
    v2 += __shfl_down(v2, off);
  }
  if (lane == 0) { s1[node] = v1; s2[node] = v2; }
}

// ---------------- column sum of h (empty-row fallback) ----------------
__global__ __launch_bounds__(256) void colsum(const float* __restrict__ h,
                                              float* __restrict__ hsum, int N_) {
  int f = threadIdx.x;
  float acc = 0.f;
  for (int r = blockIdx.x; r < N_; r += gridDim.x) acc += h[(size_t)r * OUT_F + f];
  atomicAdd(&hsum[f], acc);
}

// ---------------- CSR build ----------------
__global__ void count_deg(const int* __restrict__ edges, int* __restrict__ deg, int E_) {
  int e = blockIdx.x * blockDim.x + threadIdx.x;
  if (e < E_) atomicAdd(&deg[edges[e]], 1);
}

__global__ __launch_bounds__(1024) void scan_deg(const int* __restrict__ deg,
                                                 int* __restrict__ offs, int N_) {
  __shared__ int s[1024];
  int tid = threadIdx.x;
  int chunk = (N_ + 1023) / 1024;
  int base = tid * chunk;
  int mysum = 0;
  for (int j = 0; j < chunk; ++j) {
    int idx = base + j;
    mysum += (idx < N_) ? deg[idx] : 0;
  }
  s[tid] = mysum;
  __syncthreads();
  for (int offset = 1; offset < 1024; offset <<= 1) {
    int t = (tid >= offset) ? s[tid - offset] : 0;
    __syncthreads();
    s[tid] += t;
    __syncthreads();
  }
  int run = s[tid] - mysum;
  for (int j = 0; j < chunk; ++j) {
    int idx = base + j;
    if (idx < N_) { offs[idx] = run; run += deg[idx]; }
  }
  if (tid == 1023) offs[N_] = s[1023];
}

__global__ void fill_csr(const int* __restrict__ edges, const int* __restrict__ offs,
                         int* __restrict__ cursor, int* __restrict__ csr, int E_) {
  int e = blockIdx.x * blockDim.x + threadIdx.x;
  if (e >= E_) return;
  int srcv = edges[e];
  int tgtv = edges[E_ + e];
  int pos = offs[srcv] + atomicAdd(&cursor[srcv], 1);
  csr[pos] = tgtv;
}

// ---------------- per-row: merge duplicates, softmax, weighted gather ----------------
__global__ __launch_bounds__(256) void row_softmax(const float* __restrict__ h,
                                                   const float* __restrict__ s1,
                                                   const float* __restrict__ s2,
                                                   const int* __restrict__ offs,
                                                   const int* __restrict__ csr,
                                                   const float* __restrict__ hsum,
                                                   float* __restrict__ out, int N_) {
  const int row = blockIdx.x;
  const int tid = threadIdx.x;  // 0..255 == feature index
  const int lane = tid & 63, wave = tid >> 6;
  const int o0 = offs[row];
  int deg = offs[row + 1] - o0;
  if (deg > CAP) deg = CAP;  // unreachable (Poisson(32)); safety clamp

  __shared__ int s_tgt[CAP];
  __shared__ float s_w[CAP];
  __shared__ float s_red[8];

  const float invN = 1.0f / (float)N_;
  if (deg == 0) {
    out[(size_t)row * OUT_F + tid] = hsum[tid] * invN;
    return;
  }

  // stage targets + raw leaky scores (duplicates get identical raw scores)
  float s1i = s1[row];
  for (int p = tid; p < deg; p += 256) {
    int t = csr[o0 + p];
    s_tgt[p] = t;
    float s = s1i + s2[t];
    s_w[p] = (s > 0.f) ? s : ALPHA * s;
  }
  __syncthreads();

  // duplicate merge: leader slot gets cnt*score, others -inf (own-slot r/w only)
  for (int p = tid; p < deg; p += 256) {
    int t = s_tgt[p];
    int first = p, cnt = 0;
    for (int q = 0; q < deg; ++q) {
      int tq = s_tgt[q];
      cnt += (tq == t);
      if (tq == t && q < first) first = q;
    }
    float v;
    if (first == p) {
      v = (float)cnt * s_w[p];          // scatter-add of identical scores
      if (v == 0.f) v = -INFINITY;      // adj==0 -> NEG_BIG -> excluded
    } else {
      v = -INFINITY;
    }
    s_w[p] = v;
  }

  // block max (own slots -> wave shfl -> cross-wave LDS)
  float m = -INFINITY;
  for (int p = tid; p < deg; p += 256) m = fmaxf(m, s_w[p]);
#pragma unroll
  for (int off = 32; off; off >>= 1) m = fmaxf(m, __shfl_xor(m, off));
  if (lane == 0) s_red[wave] = m;
  __syncthreads();
  m = fmaxf(fmaxf(s_red[0], s_red[1]), fmaxf(s_red[2], s_red[3]));

  if (m == -INFINITY) {  // every merged value was exactly 0 -> uniform row
    out[(size_t)row * OUT_F + tid] = hsum[tid] * invN;
    return;
  }

  // exp (exp(-inf - m) == 0, no branch needed) + local denom partial
  float dsum = 0.f;
  for (int p = tid; p < deg; p += 256) {
    float e = __expf(s_w[p] - m);
    s_w[p] = e;
    dsum += e;
  }
#pragma unroll
  for (int off = 32; off; off >>= 1) dsum += __shfl_xor(dsum, off);
  if (lane == 0) s_red[4 + wave] = dsum;
  __syncthreads();  // covers s_red[4..7] writes AND all s_w exp-writes
  float denom = (s_red[4] + s_red[5]) + (s_red[6] + s_red[7]);
  float inv = 1.0f / denom;

  // branch-free gather, 8 independent accumulators for MLP
  const float* hf = h + tid;
  float a0 = 0.f, a1 = 0.f, a2 = 0.f, a3 = 0.f;
  float a4 = 0.f, a5 = 0.f, a6 = 0.f, a7 = 0.f;
  int p = 0;
  for (; p + 8 <= deg; p += 8) {
    int t0 = s_tgt[p],     t1 = s_tgt[p + 1], t2 = s_tgt[p + 2], t3 = s_tgt[p + 3];
    int t4 = s_tgt[p + 4], t5 = s_tgt[p + 5], t6 = s_tgt[p + 6], t7 = s_tgt[p + 7];
    float w0 = s_w[p],     w1 = s_w[p + 1], w2 = s_w[p + 2], w3 = s_w[p + 3];
    float w4 = s_w[p + 4], w5 = s_w[p + 5], w6 = s_w[p + 6], w7 = s_w[p + 7];
    a0 += w0 * hf[(size_t)t0 * OUT_F];
    a1 += w1 * hf[(size_t)t1 * OUT_F];
    a2 += w2 * hf[(size_t)t2 * OUT_F];
    a3 += w3 * hf[(size_t)t3 * OUT_F];
    a4 += w4 * hf[(size_t)t4 * OUT_F];
    a5 += w5 * hf[(size_t)t5 * OUT_F];
    a6 += w6 * hf[(size_t)t6 * OUT_F];
    a7 += w7 * hf[(size_t)t7 * OUT_F];
  }
  for (; p < deg; ++p) a0 += s_w[p] * hf[(size_t)s_tgt[p] * OUT_F];
  float acc = ((a0 + a1) + (a2 + a3)) + ((a4 + a5) + (a6 + a7));
  out[(size_t)row * OUT_F + tid] = acc * inv;
}

extern "C" void kernel_launch(void* const* d_in, const int* in_sizes, int n_in,
                              void* d_out, int out_size, void* d_ws, size_t ws_size,
                              hipStream_t stream) {
  const float* x = (const float*)d_in[0];
  const float* W = (const float*)d_in[1];
  const float* b = (const float*)d_in[2];
  const float* a = (const float*)d_in[3];
  const int* edges = (const int*)d_in[4];
  float* out = (float*)d_out;

  int N_ = in_sizes[0] / IN_F;   // 10000
  int E_ = in_sizes[4] / 2;      // 320000

  char* ws = (char*)d_ws;
  size_t off = 0;
  auto alloc = [&](size_t bytes) {
    char* p = ws + off;
    off = (off + bytes + 255) & ~(size_t)255;
    return p;
  };
  float* h      = (float*)alloc((size_t)N_ * OUT_F * sizeof(float));
  float* s1     = (float*)alloc((size_t)N_ * sizeof(float));
  float* s2     = (float*)alloc((size_t)N_ * sizeof(float));
  float* hsum   = (float*)alloc(OUT_F * sizeof(float));
  int*   deg    = (int*)alloc((size_t)N_ * sizeof(int));
  int*   offs   = (int*)alloc((size_t)(N_ + 1) * sizeof(int));
  int*   cursor = (int*)alloc((size_t)N_ * sizeof(int));
  int*   csr    = (int*)alloc((size_t)E_ * sizeof(int));

  hipMemsetAsync(hsum, 0, OUT_F * sizeof(float), stream);
  hipMemsetAsync(deg, 0, (size_t)N_ * sizeof(int), stream);
  hipMemsetAsync(cursor, 0, (size_t)N_ * sizeof(int), stream);

  dim3 ggrid((N_ + 63) / 64, OUT_F / 64);
  gemm_h_mfma<<<ggrid, 256, 0, stream>>>(x, W, b, h, N_);
  score_nodes<<<(N_ + 3) / 4, 256, 0, stream>>>(h, a, s1, s2, N_);
  colsum<<<64, 256, 0, stream>>>(h, hsum, N_);
  count_deg<<<(E_ + 255) / 256, 256, 0, stream>>>(edges, deg, E_);
  scan_deg<<<1, 1024, 0, stream>>>(deg, offs, N_);
  fill_csr<<<(E_ + 255) / 256, 256, 0, stream>>>(edges, offs, cursor, csr, E_);
  row_softmax<<<N_, 256, 0, stream>>>(h, s1, s2, offs, csr, hsum, out, N_);
}

// Round 4
// 139.148 us; speedup vs baseline: 2.1952x; 1.2321x over previous
//
#include <hip/hip_runtime.h>
#include <hip/hip_bf16.h>
#include <math.h>

#define IN_F 512
#define OUT_F 256
#define ALPHA 0.2f
#define CAP 512   // max row degree; deg ~ Poisson(32), P(deg>512) astronomically small

typedef __attribute__((ext_vector_type(8))) short bf16x8;
typedef __attribute__((ext_vector_type(8))) unsigned short u16x8;
typedef __attribute__((ext_vector_type(4))) float f32x4;

static __device__ __forceinline__ unsigned short f2bf(float f) {
  unsigned int u = __builtin_bit_cast(unsigned int, f);
  unsigned int r = (u + 0x7FFFu + ((u >> 16) & 1u)) >> 16;  // RNE
  return (unsigned short)r;
}
static __device__ __forceinline__ float bf2f(unsigned short v) {
  unsigned int u = ((unsigned int)v) << 16;
  return __builtin_bit_cast(float, u);
}

// ---------------- init: zero accumulated buffers in ONE dispatch ----------------
__global__ __launch_bounds__(256) void init_zero(int* __restrict__ deg,
                                                 float* __restrict__ hsum,
                                                 int* __restrict__ gcount, int N_) {
  int i = blockIdx.x * 256 + threadIdx.x;
  if (i < N_) deg[i] = 0;
  if (i < OUT_F) hsum[i] = 0.f;
  if (i == 0) *gcount = 0;
}

// ---------------- fp32 -> bf16 pre-convert for x and W ----------------
__global__ __launch_bounds__(256) void conv_bf16(const float* __restrict__ x,
                                                 const float* __restrict__ W,
                                                 unsigned short* __restrict__ xb,
                                                 unsigned short* __restrict__ Wb,
                                                 int nx4, int nw4) {
  int total4 = nx4 + nw4;
  for (int i4 = blockIdx.x * 256 + threadIdx.x; i4 < total4; i4 += gridDim.x * 256) {
    float4 v = (i4 < nx4) ? ((const float4*)x)[i4] : ((const float4*)W)[i4 - nx4];
    ushort4 o;
    o.x = f2bf(v.x); o.y = f2bf(v.y); o.z = f2bf(v.z); o.w = f2bf(v.w);
    if (i4 < nx4) ((ushort4*)xb)[i4] = o;
    else          ((ushort4*)Wb)[i4 - nx4] = o;
  }
}

// ---------------- GEMM (bf16 MFMA): h = x @ W^T + b; also writes bf16 copy ----------------
__global__ __launch_bounds__(256) void gemm_h_mfma(const unsigned short* __restrict__ xb,
                                                   const unsigned short* __restrict__ Wb,
                                                   const float* __restrict__ bias,
                                                   float* __restrict__ h,
                                                   unsigned short* __restrict__ hb, int N_) {
  __shared__ unsigned short lA[64][72];  // pad to 72: rows 8 apart alias 2-way (free)
  __shared__ unsigned short lB[64][72];
  const int bm = blockIdx.x * 64;
  const int bn = blockIdx.y * 64;
  const int tid = threadIdx.x;
  const int wave = tid >> 6, lane = tid & 63;
  const int wr = wave >> 1, wc = wave & 1;
  const int lr = lane & 15, lk = lane >> 4;

  f32x4 acc[2][2] = {};

  for (int k0 = 0; k0 < IN_F; k0 += 64) {
#pragma unroll
    for (int r = 0; r < 2; ++r) {
      int idx = tid + r * 256;          // 0..511 -> 64 rows x 8 col-groups
      int row = idx >> 3, c8 = (idx & 7) * 8;
      int gm = bm + row;
      u16x8 va = {0, 0, 0, 0, 0, 0, 0, 0};
      if (gm < N_) va = *(const u16x8*)&xb[(size_t)gm * IN_F + k0 + c8];
      *(u16x8*)&lA[row][c8] = va;
      u16x8 vb = *(const u16x8*)&Wb[(size_t)(bn + row) * IN_F + k0 + c8];
      *(u16x8*)&lB[row][c8] = vb;
    }
    __syncthreads();
#pragma unroll
    for (int kk = 0; kk < 64; kk += 32) {
      bf16x8 af[2], bfr[2];
#pragma unroll
      for (int fm = 0; fm < 2; ++fm)
        af[fm] = *(const bf16x8*)&lA[wr * 32 + fm * 16 + lr][kk + lk * 8];
#pragma unroll
      for (int fn = 0; fn < 2; ++fn)
        bfr[fn] = *(const bf16x8*)&lB[wc * 32 + fn * 16 + lr][kk + lk * 8];
#pragma unroll
      for (int fm = 0; fm < 2; ++fm)
#pragma unroll
        for (int fn = 0; fn < 2; ++fn)
          acc[fm][fn] = __builtin_amdgcn_mfma_f32_16x16x32_bf16(af[fm], bfr[fn],
                                                                acc[fm][fn], 0, 0, 0);
    }
    __syncthreads();
  }

  // C/D layout: col=lane&15, row=(lane>>4)*4+reg
#pragma unroll
  for (int fm = 0; fm < 2; ++fm) {
#pragma unroll
    for (int i = 0; i < 4; ++i) {
      int gr = bm + wr * 32 + fm * 16 + lk * 4 + i;
      if (gr >= N_) continue;
#pragma unroll
      for (int fn = 0; fn < 2; ++fn) {
        int gc = bn + wc * 32 + fn * 16 + lr;
        float v = acc[fm][fn][i] + bias[gc];
        h[(size_t)gr * OUT_F + gc] = v;
        hb[(size_t)gr * OUT_F + gc] = f2bf(v);
      }
    }
  }
}

// ---------------- fused: s1/s2 per node + column sum of h (one pass over h) ----------------
__global__ __launch_bounds__(256) void score_colsum(const float* __restrict__ h,
                                                    const float* __restrict__ a,
                                                    float* __restrict__ s1,
                                                    float* __restrict__ s2,
                                                    float* __restrict__ hsum, int N_) {
  const int wave = threadIdx.x >> 6, lane = threadIdx.x & 63;
  float c0 = 0.f, c1 = 0.f, c2 = 0.f, c3 = 0.f;
  const float a0 = a[lane], a1 = a[lane + 64], a2 = a[lane + 128], a3 = a[lane + 192];
  const float b0 = a[256 + lane], b1 = a[320 + lane], b2 = a[384 + lane], b3 = a[448 + lane];
  for (int n0 = blockIdx.x * 4; n0 < N_; n0 += gridDim.x * 4) {
    int node = n0 + wave;
    if (node < N_) {
      const float* hr = h + (size_t)node * OUT_F;
      float h0 = hr[lane], h1 = hr[lane + 64], h2 = hr[lane + 128], h3 = hr[lane + 192];
      c0 += h0; c1 += h1; c2 += h2; c3 += h3;
      float v1 = h0 * a0 + h1 * a1 + h2 * a2 + h3 * a3;
      float v2 = h0 * b0 + h1 * b1 + h2 * b2 + h3 * b3;
#pragma unroll
      for (int off = 32; off; off >>= 1) {
        v1 += __shfl_xor(v1, off);
        v2 += __shfl_xor(v2, off);
      }
      if (lane == 0) { s1[node] = v1; s2[node] = v2; }
    }
  }
  atomicAdd(&hsum[lane], c0);
  atomicAdd(&hsum[lane + 64], c1);
  atomicAdd(&hsum[lane + 128], c2);
  atomicAdd(&hsum[lane + 192], c3);
}

// ---------------- CSR build (no scan: parallel atomic slot reservation) ----------------
__global__ void count_deg(const int* __restrict__ edges, int* __restrict__ deg, int E_) {
  int e = blockIdx.x * blockDim.x + threadIdx.x;
  if (e < E_) atomicAdd(&deg[edges[e]], 1);
}

__global__ __launch_bounds__(256) void assign_offs(const int* __restrict__ deg,
                                                   int* __restrict__ offs,
                                                   int* __restrict__ cursor,
                                                   int* __restrict__ gcount, int N_) {
  int r = blockIdx.x * 256 + threadIdx.x;
  if (r < N_) {
    offs[r] = atomicAdd(gcount, deg[r]);  // arbitrary order, contiguous per row
    cursor[r] = 0;
  }
}

__global__ void fill_csr(const int* __restrict__ edges, const int* __restrict__ offs,
                         int* __restrict__ cursor, int* __restrict__ csr, int E_) {
  int e = blockIdx.x * blockDim.x + threadIdx.x;
  if (e >= E_) return;
  int srcv = edges[e];
  int tgtv = edges[E_ + e];
  int pos = offs[srcv] + atomicAdd(&cursor[srcv], 1);
  csr[pos] = tgtv;
}

// ---------------- per-row: merge duplicates, softmax, weighted gather (bf16 h) ----------------
__global__ __launch_bounds__(256) void row_softmax(const unsigned short* __restrict__ hb,
                                                   const float* __restrict__ s1,
                                                   const float* __restrict__ s2,
                                                   const int* __restrict__ offs,
                                                   const int* __restrict__ degv,
                                                   const int* __restrict__ csr,
                                                   const float* __restrict__ hsum,
                                                   float* __restrict__ out, int N_) {
  const int row = blockIdx.x;
  const int tid = threadIdx.x;  // feature index
  const int lane = tid & 63, wave = tid >> 6;
  const int o0 = offs[row];
  int deg = degv[row];
  if (deg > CAP) deg = CAP;

  __shared__ int s_tgt[CAP];
  __shared__ float s_w[CAP];
  __shared__ float s_red[8];

  const float invN = 1.0f / (float)N_;
  if (deg == 0) {
    out[(size_t)row * OUT_F + tid] = hsum[tid] * invN;
    return;
  }

  float s1i = s1[row];
  for (int p = tid; p < deg; p += 256) {
    int t = csr[o0 + p];
    s_tgt[p] = t;
    float s = s1i + s2[t];
    s_w[p] = (s > 0.f) ? s : ALPHA * s;
  }
  __syncthreads();

  // duplicate merge: leader slot gets cnt*score, others -inf
  for (int p = tid; p < deg; p += 256) {
    int t = s_tgt[p];
    int first = p, cnt = 0;
    for (int q = 0; q < deg; ++q) {
      int tq = s_tgt[q];
      cnt += (tq == t);
      if (tq == t && q < first) first = q;
    }
    float v;
    if (first == p) {
      v = (float)cnt * s_w[p];
      if (v == 0.f) v = -INFINITY;  // adj==0 -> NEG_BIG -> excluded
    } else {
      v = -INFINITY;
    }
    s_w[p] = v;
  }

  // block max
  float m = -INFINITY;
  for (int p = tid; p < deg; p += 256) m = fmaxf(m, s_w[p]);
#pragma unroll
  for (int off = 32; off; off >>= 1) m = fmaxf(m, __shfl_xor(m, off));
  if (lane == 0) s_red[wave] = m;
  __syncthreads();
  m = fmaxf(fmaxf(s_red[0], s_red[1]), fmaxf(s_red[2], s_red[3]));

  if (m == -INFINITY) {
    out[(size_t)row * OUT_F + tid] = hsum[tid] * invN;
    return;
  }

  // exp + denom
  float dsum = 0.f;
  for (int p = tid; p < deg; p += 256) {
    float e = __expf(s_w[p] - m);
    s_w[p] = e;
    dsum += e;
  }
#pragma unroll
  for (int off = 32; off; off >>= 1) dsum += __shfl_xor(dsum, off);
  if (lane == 0) s_red[4 + wave] = dsum;
  __syncthreads();
  float denom = (s_red[4] + s_red[5]) + (s_red[6] + s_red[7]);
  float inv = 1.0f / denom;

  // branch-free gather from bf16 h, 8 independent accumulators
  const unsigned short* hf = hb + tid;
  float a0 = 0.f, a1 = 0.f, a2 = 0.f, a3 = 0.f;
  float a4 = 0.f, a5 = 0.f, a6 = 0.f, a7 = 0.f;
  int p = 0;
  for (; p + 8 <= deg; p += 8) {
    int t0 = s_tgt[p],     t1 = s_tgt[p + 1], t2 = s_tgt[p + 2], t3 = s_tgt[p + 3];
    int t4 = s_tgt[p + 4], t5 = s_tgt[p + 5], t6 = s_tgt[p + 6], t7 = s_tgt[p + 7];
    float w0 = s_w[p],     w1 = s_w[p + 1], w2 = s_w[p + 2], w3 = s_w[p + 3];
    float w4 = s_w[p + 4], w5 = s_w[p + 5], w6 = s_w[p + 6], w7 = s_w[p + 7];
    a0 += w0 * bf2f(hf[(size_t)t0 * OUT_F]);
    a1 += w1 * bf2f(hf[(size_t)t1 * OUT_F]);
    a2 += w2 * bf2f(hf[(size_t)t2 * OUT_F]);
    a3 += w3 * bf2f(hf[(size_t)t3 * OUT_F]);
    a4 += w4 * bf2f(hf[(size_t)t4 * OUT_F]);
    a5 += w5 * bf2f(hf[(size_t)t5 * OUT_F]);
    a6 += w6 * bf2f(hf[(size_t)t6 * OUT_F]);
    a7 += w7 * bf2f(hf[(size_t)t7 * OUT_F]);
  }
  for (; p < deg; ++p) a0 += s_w[p] * bf2f(hf[(size_t)s_tgt[p] * OUT_F]);
  float acc = ((a0 + a1) + (a2 + a3)) + ((a4 + a5) + (a6 + a7));
  out[(size_t)row * OUT_F + tid] = acc * inv;
}

extern "C" void kernel_launch(void* const* d_in, const int* in_sizes, int n_in,
                              void* d_out, int out_size, void* d_ws, size_t ws_size,
                              hipStream_t stream) {
  const float* x = (const float*)d_in[0];
  const float* W = (const float*)d_in[1];
  const float* b = (const float*)d_in[2];
  const float* a = (const float*)d_in[3];
  const int* edges = (const int*)d_in[4];
  float* out = (float*)d_out;

  int N_ = in_sizes[0] / IN_F;   // 10000
  int E_ = in_sizes[4] / 2;      // 320000

  char* ws = (char*)d_ws;
  size_t off = 0;
  auto alloc = [&](size_t bytes) {
    char* p = ws + off;
    off = (off + bytes + 255) & ~(size_t)255;
    return p;
  };
  float*          h      = (float*)alloc((size_t)N_ * OUT_F * sizeof(float));
  unsigned short* hb     = (unsigned short*)alloc((size_t)N_ * OUT_F * sizeof(unsigned short));
  unsigned short* xb     = (unsigned short*)alloc((size_t)N_ * IN_F * sizeof(unsigned short));
  unsigned short* Wb     = (unsigned short*)alloc((size_t)OUT_F * IN_F * sizeof(unsigned short));
  float*          s1     = (float*)alloc((size_t)N_ * sizeof(float));
  float*          s2     = (float*)alloc((size_t)N_ * sizeof(float));
  float*          hsum   = (float*)alloc(OUT_F * sizeof(float));
  int*            deg    = (int*)alloc((size_t)N_ * sizeof(int));
  int*            offs   = (int*)alloc((size_t)N_ * sizeof(int));
  int*            cursor = (int*)alloc((size_t)N_ * sizeof(int));
  int*            gcount = (int*)alloc(sizeof(int));
  int*            csr    = (int*)alloc((size_t)E_ * sizeof(int));

  int nx4 = N_ * IN_F / 4, nw4 = OUT_F * IN_F / 4;

  init_zero<<<(N_ + 255) / 256, 256, 0, stream>>>(deg, hsum, gcount, N_);
  conv_bf16<<<1024, 256, 0, stream>>>(x, W, xb, Wb, nx4, nw4);
  dim3 ggrid((N_ + 63) / 64, OUT_F / 64);
  gemm_h_mfma<<<ggrid, 256, 0, stream>>>(xb, Wb, b, h, hb, N_);
  score_colsum<<<160, 256, 0, stream>>>(h, a, s1, s2, hsum, N_);
  count_deg<<<(E_ + 255) / 256, 256, 0, stream>>>(edges, deg, E_);
  assign_offs<<<(N_ + 255) / 256, 256, 0, stream>>>(deg, offs, cursor, gcount, N_);
  fill_csr<<<(E_ + 255) / 256, 256, 0, stream>>>(edges, offs, cursor, csr, E_);
  row_softmax<<<N_, 256, 0, stream>>>(hb, s1, s2, offs, deg, csr, hsum, out, N_);
}

// Round 5
// 115.512 us; speedup vs baseline: 2.6444x; 1.2046x over previous
//
#include <hip/hip_runtime.h>
#include <hip/hip_bf16.h>
#include <math.h>

#define IN_F 512
#define OUT_F 256
#define ALPHA 0.2f
#define CAP 512   // max row degree; deg ~ Poisson(32), P(deg>512) astronomically small

typedef __attribute__((ext_vector_type(8))) short bf16x8;
typedef __attribute__((ext_vector_type(8))) unsigned short u16x8;
typedef __attribute__((ext_vector_type(4))) float f32x4;

static __device__ __forceinline__ unsigned short f2bf(float f) {
  unsigned int u = __builtin_bit_cast(unsigned int, f);
  unsigned int r = (u + 0x7FFFu + ((u >> 16) & 1u)) >> 16;  // RNE
  return (unsigned short)r;
}
static __device__ __forceinline__ float bf2f(unsigned short v) {
  unsigned int u = ((unsigned int)v) << 16;
  return __builtin_bit_cast(float, u);
}

// ---------------- prep: x,W -> bf16  +  zero all atomically-accumulated buffers ----------------
__global__ __launch_bounds__(256) void prep(const float* __restrict__ x,
                                            const float* __restrict__ W,
                                            unsigned short* __restrict__ xb,
                                            unsigned short* __restrict__ Wb,
                                            int* __restrict__ deg,
                                            float* __restrict__ s1,
                                            float* __restrict__ s2,
                                            float* __restrict__ hsum,
                                            int* __restrict__ gcount,
                                            int nx4, int nw4, int N_) {
  const int stride = gridDim.x * 256;
  const int tid0 = blockIdx.x * 256 + threadIdx.x;
  int total4 = nx4 + nw4;
  for (int i4 = tid0; i4 < total4; i4 += stride) {
    float4 v = (i4 < nx4) ? ((const float4*)x)[i4] : ((const float4*)W)[i4 - nx4];
    ushort4 o;
    o.x = f2bf(v.x); o.y = f2bf(v.y); o.z = f2bf(v.z); o.w = f2bf(v.w);
    if (i4 < nx4) ((ushort4*)xb)[i4] = o;
    else          ((ushort4*)Wb)[i4 - nx4] = o;
  }
  for (int i = tid0; i < N_; i += stride) {
    deg[i] = 0; s1[i] = 0.f; s2[i] = 0.f;
    if (i < OUT_F) hsum[i] = 0.f;
    if (i == 0) *gcount = 0;
  }
}

// ---------------- GEMM (bf16 MFMA) + fused epilogue: hb, s1/s2 partial dots, hsum colsum ----------------
__global__ __launch_bounds__(256) void gemm_fused(const unsigned short* __restrict__ xb,
                                                  const unsigned short* __restrict__ Wb,
                                                  const float* __restrict__ bias,
                                                  const float* __restrict__ a,
                                                  unsigned short* __restrict__ hb,
                                                  float* __restrict__ s1,
                                                  float* __restrict__ s2,
                                                  float* __restrict__ hsum, int N_) {
  __shared__ unsigned short lA[64][72];  // pad 72: rows 8 apart alias banks 2-way (free)
  __shared__ unsigned short lB[64][72];
  const int bm = blockIdx.x * 64;
  const int bn = blockIdx.y * 64;
  const int tid = threadIdx.x;
  const int wave = tid >> 6, lane = tid & 63;
  const int wr = wave >> 1, wc = wave & 1;
  const int lr = lane & 15, lk = lane >> 4;

  f32x4 acc[2][2] = {};

  for (int k0 = 0; k0 < IN_F; k0 += 64) {
#pragma unroll
    for (int r = 0; r < 2; ++r) {
      int idx = tid + r * 256;          // 0..511 -> 64 rows x 8 col-groups
      int row = idx >> 3, c8 = (idx & 7) * 8;
      int gm = bm + row;
      u16x8 va = {0, 0, 0, 0, 0, 0, 0, 0};
      if (gm < N_) va = *(const u16x8*)&xb[(size_t)gm * IN_F + k0 + c8];
      *(u16x8*)&lA[row][c8] = va;
      u16x8 vb = *(const u16x8*)&Wb[(size_t)(bn + row) * IN_F + k0 + c8];
      *(u16x8*)&lB[row][c8] = vb;
    }
    __syncthreads();
#pragma unroll
    for (int kk = 0; kk < 64; kk += 32) {
      bf16x8 af[2], bfr[2];
#pragma unroll
      for (int fm = 0; fm < 2; ++fm)
        af[fm] = *(const bf16x8*)&lA[wr * 32 + fm * 16 + lr][kk + lk * 8];
#pragma unroll
      for (int fn = 0; fn < 2; ++fn)
        bfr[fn] = *(const bf16x8*)&lB[wc * 32 + fn * 16 + lr][kk + lk * 8];
#pragma unroll
      for (int fm = 0; fm < 2; ++fm)
#pragma unroll
        for (int fn = 0; fn < 2; ++fn)
          acc[fm][fn] = __builtin_amdgcn_mfma_f32_16x16x32_bf16(af[fm], bfr[fn],
                                                                acc[fm][fn], 0, 0, 0);
    }
    __syncthreads();
  }

  // ---- fused epilogue. C/D layout: col=lane&15, row=(lane>>4)*4+reg ----
  int gc[2];
  float av[2], bv[2], biasv[2], csum[2] = {0.f, 0.f};
#pragma unroll
  for (int fn = 0; fn < 2; ++fn) {
    gc[fn] = bn + wc * 32 + fn * 16 + lr;
    av[fn] = a[gc[fn]];
    bv[fn] = a[OUT_F + gc[fn]];
    biasv[fn] = bias[gc[fn]];
  }
#pragma unroll
  for (int fm = 0; fm < 2; ++fm) {
#pragma unroll
    for (int i = 0; i < 4; ++i) {
      int gr = bm + wr * 32 + fm * 16 + lk * 4 + i;
      bool valid = (gr < N_);
      float v0 = valid ? acc[fm][0][i] + biasv[0] : 0.f;
      float v1 = valid ? acc[fm][1][i] + biasv[1] : 0.f;
      if (valid) {
        hb[(size_t)gr * OUT_F + gc[0]] = f2bf(v0);
        hb[(size_t)gr * OUT_F + gc[1]] = f2bf(v1);
      }
      csum[0] += v0; csum[1] += v1;
      // s1/s2 partials for row gr: reduce over this block's 64 cols.
      // cols live across the 16-lane lr-group (xor 1,2,4,8); two wc-waves atomic separately.
      float p1 = v0 * av[0] + v1 * av[1];
      float p2 = v0 * bv[0] + v1 * bv[1];
#pragma unroll
      for (int off = 1; off < 16; off <<= 1) {
        p1 += __shfl_xor(p1, off);
        p2 += __shfl_xor(p2, off);
      }
      if (lr == 0 && valid) {
        atomicAdd(&s1[gr], p1);
        atomicAdd(&s2[gr], p2);
      }
    }
  }
  // hsum colsum: rows live across lk-groups (xor 16,32); two wr-waves atomic separately.
#pragma unroll
  for (int off = 16; off < 64; off <<= 1) {
    csum[0] += __shfl_xor(csum[0], off);
    csum[1] += __shfl_xor(csum[1], off);
  }
  if (lk == 0) {
    atomicAdd(&hsum[gc[0]], csum[0]);
    atomicAdd(&hsum[gc[1]], csum[1]);
  }
}

// ---------------- CSR build ----------------
__global__ void count_deg(const int* __restrict__ edges, int* __restrict__ deg, int E_) {
  int e = blockIdx.x * blockDim.x + threadIdx.x;
  if (e < E_) atomicAdd(&deg[edges[e]], 1);
}

__global__ __launch_bounds__(256) void assign_offs(const int* __restrict__ deg,
                                                   int* __restrict__ offs,
                                                   int* __restrict__ cursor,
                                                   int* __restrict__ gcount, int N_) {
  int r = blockIdx.x * 256 + threadIdx.x;
  if (r < N_) {
    offs[r] = atomicAdd(gcount, deg[r]);  // arbitrary order, contiguous per row
    cursor[r] = 0;
  }
}

__global__ void fill_csr(const int* __restrict__ edges, const int* __restrict__ offs,
                         int* __restrict__ cursor, int* __restrict__ csr, int E_) {
  int e = blockIdx.x * blockDim.x + threadIdx.x;
  if (e >= E_) return;
  int srcv = edges[e];
  int tgtv = edges[E_ + e];
  int pos = offs[srcv] + atomicAdd(&cursor[srcv], 1);
  csr[pos] = tgtv;
}

// ---------------- per-row: merge duplicates, softmax, weighted gather (bf16 h) ----------------
__global__ __launch_bounds__(256) void row_softmax(const unsigned short* __restrict__ hb,
                                                   const float* __restrict__ s1,
                                                   const float* __restrict__ s2,
                                                   const int* __restrict__ offs,
                                                   const int* __restrict__ degv,
                                                   const int* __restrict__ csr,
                                                   const float* __restrict__ hsum,
                                                   float* __restrict__ out, int N_) {
  const int row = blockIdx.x;
  const int tid = threadIdx.x;  // feature index
  const int lane = tid & 63, wave = tid >> 6;
  const int o0 = offs[row];
  int deg = degv[row];
  if (deg > CAP) deg = CAP;

  __shared__ int s_tgt[CAP];
  __shared__ float s_w[CAP];
  __shared__ float s_red[8];

  const float invN = 1.0f / (float)N_;
  if (deg == 0) {
    out[(size_t)row * OUT_F + tid] = hsum[tid] * invN;
    return;
  }

  float s1i = s1[row];
  for (int p = tid; p < deg; p += 256) {
    int t = csr[o0 + p];
    s_tgt[p] = t;
    float s = s1i + s2[t];
    s_w[p] = (s > 0.f) ? s : ALPHA * s;
  }
  __syncthreads();

  // duplicate merge: leader slot gets cnt*score, others -inf
  for (int p = tid; p < deg; p += 256) {
    int t = s_tgt[p];
    int first = p, cnt = 0;
    for (int q = 0; q < deg; ++q) {
      int tq = s_tgt[q];
      cnt += (tq == t);
      if (tq == t && q < first) first = q;
    }
    float v;
    if (first == p) {
      v = (float)cnt * s_w[p];
      if (v == 0.f) v = -INFINITY;  // adj==0 -> NEG_BIG -> excluded
    } else {
      v = -INFINITY;
    }
    s_w[p] = v;
  }

  // block max
  float m = -INFINITY;
  for (int p = tid; p < deg; p += 256) m = fmaxf(m, s_w[p]);
#pragma unroll
  for (int off = 32; off; off >>= 1) m = fmaxf(m, __shfl_xor(m, off));
  if (lane == 0) s_red[wave] = m;
  __syncthreads();
  m = fmaxf(fmaxf(s_red[0], s_red[1]), fmaxf(s_red[2], s_red[3]));

  if (m == -INFINITY) {
    out[(size_t)row * OUT_F + tid] = hsum[tid] * invN;
    return;
  }

  // exp + denom
  float dsum = 0.f;
  for (int p = tid; p < deg; p += 256) {
    float e = __expf(s_w[p] - m);
    s_w[p] = e;
    dsum += e;
  }
#pragma unroll
  for (int off = 32; off; off >>= 1) dsum += __shfl_xor(dsum, off);
  if (lane == 0) s_red[4 + wave] = dsum;
  __syncthreads();
  float denom = (s_red[4] + s_red[5]) + (s_red[6] + s_red[7]);
  float inv = 1.0f / denom;

  // branch-free gather from bf16 h, 8 independent accumulators
  const unsigned short* hf = hb + tid;
  float a0 = 0.f, a1 = 0.f, a2 = 0.f, a3 = 0.f;
  float a4 = 0.f, a5 = 0.f, a6 = 0.f, a7 = 0.f;
  int p = 0;
  for (; p + 8 <= deg; p += 8) {
    int t0 = s_tgt[p],     t1 = s_tgt[p + 1], t2 = s_tgt[p + 2], t3 = s_tgt[p + 3];
    int t4 = s_tgt[p + 4], t5 = s_tgt[p + 5], t6 = s_tgt[p + 6], t7 = s_tgt[p + 7];
    float w0 = s_w[p],     w1 = s_w[p + 1], w2 = s_w[p + 2], w3 = s_w[p + 3];
    float w4 = s_w[p + 4], w5 = s_w[p + 5], w6 = s_w[p + 6], w7 = s_w[p + 7];
    a0 += w0 * bf2f(hf[(size_t)t0 * OUT_F]);
    a1 += w1 * bf2f(hf[(size_t)t1 * OUT_F]);
    a2 += w2 * bf2f(hf[(size_t)t2 * OUT_F]);
    a3 += w3 * bf2f(hf[(size_t)t3 * OUT_F]);
    a4 += w4 * bf2f(hf[(size_t)t4 * OUT_F]);
    a5 += w5 * bf2f(hf[(size_t)t5 * OUT_F]);
    a6 += w6 * bf2f(hf[(size_t)t6 * OUT_F]);
    a7 += w7 * bf2f(hf[(size_t)t7 * OUT_F]);
  }
  for (; p < deg; ++p) a0 += s_w[p] * bf2f(hf[(size_t)s_tgt[p] * OUT_F]);
  float acc = ((a0 + a1) + (a2 + a3)) + ((a4 + a5) + (a6 + a7));
  out[(size_t)row * OUT_F + tid] = acc * inv;
}

extern "C" void kernel_launch(void* const* d_in, const int* in_sizes, int n_in,
                              void* d_out, int out_size, void* d_ws, size_t ws_size,
                              hipStream_t stream) {
  const float* x = (const float*)d_in[0];
  const float* W = (const float*)d_in[1];
  const float* b = (const float*)d_in[2];
  const float* a = (const float*)d_in[3];
  const int* edges = (const int*)d_in[4];
  float* out = (float*)d_out;

  int N_ = in_sizes[0] / IN_F;   // 10000
  int E_ = in_sizes[4] / 2;      // 320000

  char* ws = (char*)d_ws;
  size_t off = 0;
  auto alloc = [&](size_t bytes) {
    char* p = ws + off;
    off = (off + bytes + 255) & ~(size_t)255;
    return p;
  };
  unsigned short* hb     = (unsigned short*)alloc((size_t)N_ * OUT_F * sizeof(unsigned short));
  unsigned short* xb     = (unsigned short*)alloc((size_t)N_ * IN_F * sizeof(unsigned short));
  unsigned short* Wb     = (unsigned short*)alloc((size_t)OUT_F * IN_F * sizeof(unsigned short));
  float*          s1     = (float*)alloc((size_t)N_ * sizeof(float));
  float*          s2     = (float*)alloc((size_t)N_ * sizeof(float));
  float*          hsum   = (float*)alloc(OUT_F * sizeof(float));
  int*            deg    = (int*)alloc((size_t)N_ * sizeof(int));
  int*            offs   = (int*)alloc((size_t)N_ * sizeof(int));
  int*            cursor = (int*)alloc((size_t)N_ * sizeof(int));
  int*            gcount = (int*)alloc(sizeof(int));
  int*            csr    = (int*)alloc((size_t)E_ * sizeof(int));

  int nx4 = N_ * IN_F / 4, nw4 = OUT_F * IN_F / 4;

  prep<<<1024, 256, 0, stream>>>(x, W, xb, Wb, deg, s1, s2, hsum, gcount, nx4, nw4, N_);
  dim3 ggrid((N_ + 63) / 64, OUT_F / 64);
  gemm_fused<<<ggrid, 256, 0, stream>>>(xb, Wb, b, a, hb, s1, s2, hsum, N_);
  count_deg<<<(E_ + 255) / 256, 256, 0, stream>>>(edges, deg, E_);
  assign_offs<<<(N_ + 255) / 256, 256, 0, stream>>>(deg, offs, cursor, gcount, N_);
  fill_csr<<<(E_ + 255) / 256, 256, 0, stream>>>(edges, offs, cursor, csr, E_);
  row_softmax<<<N_, 256, 0, stream>>>(hb, s1, s2, offs, deg, csr, hsum, out, N_);
}

// Round 6
// 76.082 us; speedup vs baseline: 4.0149x; 1.5183x over previous
//
#include <hip/hip_runtime.h>
#include <hip/hip_bf16.h>
#include <math.h>

#define IN_F 512
#define OUT_F 256
#define ALPHA 0.2f
#define CAP 512     // max row degree; deg ~ Poisson(32), P(deg>512) astronomically small
#define NCHAIN 16   // sub-chains per row for parallel linked-list traversal

typedef __attribute__((ext_vector_type(8))) short bf16x8;
typedef __attribute__((ext_vector_type(8))) unsigned short u16x8;
typedef __attribute__((ext_vector_type(4))) float f32x4;

static __device__ __forceinline__ unsigned short f2bf(float f) {
  unsigned int u = __builtin_bit_cast(unsigned int, f);
  unsigned int r = (u + 0x7FFFu + ((u >> 16) & 1u)) >> 16;  // RNE
  return (unsigned short)r;
}
static __device__ __forceinline__ float bf2f(unsigned short v) {
  unsigned int u = ((unsigned int)v) << 16;
  return __builtin_bit_cast(float, u);
}

// ---------------- prep: x,W -> bf16 + init head=-1, zero s1/s2/hsum ----------------
__global__ __launch_bounds__(256) void prep(const float* __restrict__ x,
                                            const float* __restrict__ W,
                                            unsigned short* __restrict__ xb,
                                            unsigned short* __restrict__ Wb,
                                            int* __restrict__ head,
                                            float* __restrict__ s1,
                                            float* __restrict__ s2,
                                            float* __restrict__ hsum,
                                            int nx4, int nw4, int N_) {
  const int stride = gridDim.x * 256;
  const int tid0 = blockIdx.x * 256 + threadIdx.x;
  int total4 = nx4 + nw4;
  for (int i4 = tid0; i4 < total4; i4 += stride) {
    float4 v = (i4 < nx4) ? ((const float4*)x)[i4] : ((const float4*)W)[i4 - nx4];
    ushort4 o;
    o.x = f2bf(v.x); o.y = f2bf(v.y); o.z = f2bf(v.z); o.w = f2bf(v.w);
    if (i4 < nx4) ((ushort4*)xb)[i4] = o;
    else          ((ushort4*)Wb)[i4 - nx4] = o;
  }
  int nh = NCHAIN * N_;
  for (int i = tid0; i < nh; i += stride) head[i] = -1;
  for (int i = tid0; i < N_; i += stride) { s1[i] = 0.f; s2[i] = 0.f; }
  if (tid0 < OUT_F) hsum[tid0] = 0.f;
}

// ---------------- mega: [0,gblocks) = GEMM+epilogue, [gblocks,..) = edge fill ----------------
__global__ __launch_bounds__(256) void mega(const unsigned short* __restrict__ xb,
                                            const unsigned short* __restrict__ Wb,
                                            const float* __restrict__ bias,
                                            const float* __restrict__ a,
                                            unsigned short* __restrict__ hb,
                                            float* __restrict__ s1,
                                            float* __restrict__ s2,
                                            float* __restrict__ hsum,
                                            const int* __restrict__ edges,
                                            int* __restrict__ head,
                                            int2* __restrict__ rec,
                                            int N_, int E_, int mtiles, int gblocks) {
  __shared__ unsigned short lA[64][72];  // pad 72: rows 8 apart alias banks 2-way (free)
  __shared__ unsigned short lB[64][72];
  const int bid = blockIdx.x;
  const int tid = threadIdx.x;

  if (bid >= gblocks) {
    // ---- edge fill: 16-way per-row linked lists ----
    int idx = (bid - gblocks) * 256 + tid;
    if (idx < E_) {
      int srcv = edges[idx];
      int tgtv = edges[E_ + idx];
      int c = idx & (NCHAIN - 1);
      int old = atomicExch(&head[srcv * NCHAIN + c], idx);
      rec[idx] = make_int2(old, tgtv);
    }
    return;
  }

  // ---- GEMM tile ----
  const int bm = (bid % mtiles) * 64;
  const int bn = (bid / mtiles) * 64;
  const int wave = tid >> 6, lane = tid & 63;
  const int wr = wave >> 1, wc = wave & 1;
  const int lr = lane & 15, lk = lane >> 4;

  f32x4 acc[2][2] = {};

  for (int k0 = 0; k0 < IN_F; k0 += 64) {
#pragma unroll
    for (int r = 0; r < 2; ++r) {
      int idx = tid + r * 256;          // 0..511 -> 64 rows x 8 col-groups
      int row = idx >> 3, c8 = (idx & 7) * 8;
      int gm = bm + row;
      u16x8 va = {0, 0, 0, 0, 0, 0, 0, 0};
      if (gm < N_) va = *(const u16x8*)&xb[(size_t)gm * IN_F + k0 + c8];
      *(u16x8*)&lA[row][c8] = va;
      u16x8 vb = *(const u16x8*)&Wb[(size_t)(bn + row) * IN_F + k0 + c8];
      *(u16x8*)&lB[row][c8] = vb;
    }
    __syncthreads();
#pragma unroll
    for (int kk = 0; kk < 64; kk += 32) {
      bf16x8 af[2], bfr[2];
#pragma unroll
      for (int fm = 0; fm < 2; ++fm)
        af[fm] = *(const bf16x8*)&lA[wr * 32 + fm * 16 + lr][kk + lk * 8];
#pragma unroll
      for (int fn = 0; fn < 2; ++fn)
        bfr[fn] = *(const bf16x8*)&lB[wc * 32 + fn * 16 + lr][kk + lk * 8];
#pragma unroll
      for (int fm = 0; fm < 2; ++fm)
#pragma unroll
        for (int fn = 0; fn < 2; ++fn)
          acc[fm][fn] = __builtin_amdgcn_mfma_f32_16x16x32_bf16(af[fm], bfr[fn],
                                                                acc[fm][fn], 0, 0, 0);
    }
    __syncthreads();
  }

  // ---- fused epilogue. C/D layout: col=lane&15, row=(lane>>4)*4+reg ----
  int gc[2];
  float av[2], bv[2], biasv[2], csum[2] = {0.f, 0.f};
#pragma unroll
  for (int fn = 0; fn < 2; ++fn) {
    gc[fn] = bn + wc * 32 + fn * 16 + lr;
    av[fn] = a[gc[fn]];
    bv[fn] = a[OUT_F + gc[fn]];
    biasv[fn] = bias[gc[fn]];
  }
#pragma unroll
  for (int fm = 0; fm < 2; ++fm) {
#pragma unroll
    for (int i = 0; i < 4; ++i) {
      int gr = bm + wr * 32 + fm * 16 + lk * 4 + i;
      bool valid = (gr < N_);
      float v0 = valid ? acc[fm][0][i] + biasv[0] : 0.f;
      float v1 = valid ? acc[fm][1][i] + biasv[1] : 0.f;
      if (valid) {
        hb[(size_t)gr * OUT_F + gc[0]] = f2bf(v0);
        hb[(size_t)gr * OUT_F + gc[1]] = f2bf(v1);
      }
      csum[0] += v0; csum[1] += v1;
      float p1 = v0 * av[0] + v1 * av[1];
      float p2 = v0 * bv[0] + v1 * bv[1];
#pragma unroll
      for (int off = 1; off < 16; off <<= 1) {
        p1 += __shfl_xor(p1, off);
        p2 += __shfl_xor(p2, off);
      }
      if (lr == 0 && valid) {
        atomicAdd(&s1[gr], p1);
        atomicAdd(&s2[gr], p2);
      }
    }
  }
#pragma unroll
  for (int off = 16; off < 64; off <<= 1) {
    csum[0] += __shfl_xor(csum[0], off);
    csum[1] += __shfl_xor(csum[1], off);
  }
  if (lk == 0) {
    atomicAdd(&hsum[gc[0]], csum[0]);
    atomicAdd(&hsum[gc[1]], csum[1]);
  }
}

// ---------------- per-row: traverse lists, merge dups, softmax, gather (bf16 h) ----------------
// 128 threads, each owns 2 features (uint = 2 bf16 loads).
__global__ __launch_bounds__(128) void row_softmax(const unsigned short* __restrict__ hb,
                                                   const float* __restrict__ s1,
                                                   const float* __restrict__ s2,
                                                   const int* __restrict__ head,
                                                   const int2* __restrict__ rec,
                                                   const float* __restrict__ hsum,
                                                   float* __restrict__ out, int N_) {
  const int row = blockIdx.x;
  const int tid = threadIdx.x;          // 0..127; features 2*tid, 2*tid+1
  const int lane = tid & 63, wave = tid >> 6;

  __shared__ int s_tgt[CAP];
  __shared__ float s_w[CAP];
  __shared__ int s_len[NCHAIN];
  __shared__ int s_base[NCHAIN + 1];
  __shared__ float s_red[4];

  // pass 1: chain lengths
  if (tid < NCHAIN) {
    int e = head[row * NCHAIN + tid];
    int len = 0;
    while (e >= 0) { ++len; e = rec[e].x; }
    s_len[tid] = len;
  }
  __syncthreads();
  if (tid == 0) {
    int run = 0;
#pragma unroll
    for (int c = 0; c < NCHAIN; ++c) { s_base[c] = run; run += s_len[c]; }
    s_base[NCHAIN] = run;
  }
  __syncthreads();
  int deg = s_base[NCHAIN];
  if (deg > CAP) deg = CAP;

  const float invN = 1.0f / (float)N_;
  float2* out2 = (float2*)(out + (size_t)row * OUT_F);
  if (deg == 0) {
    out2[tid] = make_float2(hsum[2 * tid] * invN, hsum[2 * tid + 1] * invN);
    return;
  }

  // pass 2: deterministic placement (layout independent of atomic timing)
  if (tid < NCHAIN) {
    int e = head[row * NCHAIN + tid];
    int i = s_base[tid];
    while (e >= 0) {
      int2 r = rec[e];
      if (i < CAP) s_tgt[i] = r.y;
      ++i;
      e = r.x;
    }
  }
  __syncthreads();

  // raw leaky scores
  float s1i = s1[row];
  for (int p = tid; p < deg; p += 128) {
    int t = s_tgt[p];
    float s = s1i + s2[t];
    s_w[p] = (s > 0.f) ? s : ALPHA * s;
  }
  __syncthreads();

  // duplicate merge: leader slot gets cnt*score, others -inf
  for (int p = tid; p < deg; p += 128) {
    int t = s_tgt[p];
    int first = p, cnt = 0;
    for (int q = 0; q < deg; ++q) {
      int tq = s_tgt[q];
      cnt += (tq == t);
      if (tq == t && q < first) first = q;
    }
    float v;
    if (first == p) {
      v = (float)cnt * s_w[p];
      if (v == 0.f) v = -INFINITY;  // adj==0 -> NEG_BIG -> excluded
    } else {
      v = -INFINITY;
    }
    s_w[p] = v;
  }

  // block max (2 waves)
  float m = -INFINITY;
  for (int p = tid; p < deg; p += 128) m = fmaxf(m, s_w[p]);
#pragma unroll
  for (int off = 32; off; off >>= 1) m = fmaxf(m, __shfl_xor(m, off));
  if (lane == 0) s_red[wave] = m;
  __syncthreads();
  m = fmaxf(s_red[0], s_red[1]);

  if (m == -INFINITY) {
    out2[tid] = make_float2(hsum[2 * tid] * invN, hsum[2 * tid + 1] * invN);
    return;
  }

  // exp + denom
  float dsum = 0.f;
  for (int p = tid; p < deg; p += 128) {
    float e = __expf(s_w[p] - m);
    s_w[p] = e;
    dsum += e;
  }
#pragma unroll
  for (int off = 32; off; off >>= 1) dsum += __shfl_xor(dsum, off);
  if (lane == 0) s_red[2 + wave] = dsum;
  __syncthreads();
  float inv = 1.0f / (s_red[2] + s_red[3]);

  // branch-free gather: uint = 2 bf16 per thread, 8 edges in flight
  const unsigned int* hu = (const unsigned int*)hb;
  float L0 = 0.f, L1 = 0.f, L2 = 0.f, L3 = 0.f, L4 = 0.f, L5 = 0.f, L6 = 0.f, L7 = 0.f;
  float H0 = 0.f, H1 = 0.f, H2 = 0.f, H3 = 0.f, H4 = 0.f, H5 = 0.f, H6 = 0.f, H7 = 0.f;
  int p = 0;
  for (; p + 8 <= deg; p += 8) {
    int t0 = s_tgt[p],     t1 = s_tgt[p + 1], t2 = s_tgt[p + 2], t3 = s_tgt[p + 3];
    int t4 = s_tgt[p + 4], t5 = s_tgt[p + 5], t6 = s_tgt[p + 6], t7 = s_tgt[p + 7];
    float w0 = s_w[p],     w1 = s_w[p + 1], w2 = s_w[p + 2], w3 = s_w[p + 3];
    float w4 = s_w[p + 4], w5 = s_w[p + 5], w6 = s_w[p + 6], w7 = s_w[p + 7];
    unsigned int u0 = hu[(size_t)t0 * 128 + tid], u1 = hu[(size_t)t1 * 128 + tid];
    unsigned int u2 = hu[(size_t)t2 * 128 + tid], u3 = hu[(size_t)t3 * 128 + tid];
    unsigned int u4 = hu[(size_t)t4 * 128 + tid], u5 = hu[(size_t)t5 * 128 + tid];
    unsigned int u6 = hu[(size_t)t6 * 128 + tid], u7 = hu[(size_t)t7 * 128 + tid];
    L0 += w0 * __builtin_bit_cast(float, u0 << 16);
    H0 += w0 * __builtin_bit_cast(float, u0 & 0xffff0000u);
    L1 += w1 * __builtin_bit_cast(float, u1 << 16);
    H1 += w1 * __builtin_bit_cast(float, u1 & 0xffff0000u);
    L2 += w2 * __builtin_bit_cast(float, u2 << 16);
    H2 += w2 * __builtin_bit_cast(float, u2 & 0xffff0000u);
    L3 += w3 * __builtin_bit_cast(float, u3 << 16);
    H3 += w3 * __builtin_bit_cast(float, u3 & 0xffff0000u);
    L4 += w4 * __builtin_bit_cast(float, u4 << 16);
    H4 += w4 * __builtin_bit_cast(float, u4 & 0xffff0000u);
    L5 += w5 * __builtin_bit_cast(float, u5 << 16);
    H5 += w5 * __builtin_bit_cast(float, u5 & 0xffff0000u);
    L6 += w6 * __builtin_bit_cast(float, u6 << 16);
    H6 += w6 * __builtin_bit_cast(float, u6 & 0xffff0000u);
    L7 += w7 * __builtin_bit_cast(float, u7 << 16);
    H7 += w7 * __builtin_bit_cast(float, u7 & 0xffff0000u);
  }
  for (; p < deg; ++p) {
    float w = s_w[p];
    unsigned int u = hu[(size_t)s_tgt[p] * 128 + tid];
    L0 += w * __builtin_bit_cast(float, u << 16);
    H0 += w * __builtin_bit_cast(float, u & 0xffff0000u);
  }
  float accL = ((L0 + L1) + (L2 + L3)) + ((L4 + L5) + (L6 + L7));
  float accH = ((H0 + H1) + (H2 + H3)) + ((H4 + H5) + (H6 + H7));
  out2[tid] = make_float2(accL * inv, accH * inv);
}

extern "C" void kernel_launch(void* const* d_in, const int* in_sizes, int n_in,
                              void* d_out, int out_size, void* d_ws, size_t ws_size,
                              hipStream_t stream) {
  const float* x = (const float*)d_in[0];
  const float* W = (const float*)d_in[1];
  const float* b = (const float*)d_in[2];
  const float* a = (const float*)d_in[3];
  const int* edges = (const int*)d_in[4];
  float* out = (float*)d_out;

  int N_ = in_sizes[0] / IN_F;   // 10000
  int E_ = in_sizes[4] / 2;      // 320000

  char* ws = (char*)d_ws;
  size_t off = 0;
  auto alloc = [&](size_t bytes) {
    char* p = ws + off;
    off = (off + bytes + 255) & ~(size_t)255;
    return p;
  };
  unsigned short* hb   = (unsigned short*)alloc((size_t)N_ * OUT_F * sizeof(unsigned short));
  unsigned short* xb   = (unsigned short*)alloc((size_t)N_ * IN_F * sizeof(unsigned short));
  unsigned short* Wb   = (unsigned short*)alloc((size_t)OUT_F * IN_F * sizeof(unsigned short));
  float*          s1   = (float*)alloc((size_t)N_ * sizeof(float));
  float*          s2   = (float*)alloc((size_t)N_ * sizeof(float));
  float*          hsum = (float*)alloc(OUT_F * sizeof(float));
  int*            head = (int*)alloc((size_t)NCHAIN * N_ * sizeof(int));
  int2*           rec  = (int2*)alloc((size_t)E_ * sizeof(int2));

  int nx4 = N_ * IN_F / 4, nw4 = OUT_F * IN_F / 4;
  int mtiles = (N_ + 63) / 64;
  int gblocks = mtiles * (OUT_F / 64);
  int fblocks = (E_ + 255) / 256;

  prep<<<1024, 256, 0, stream>>>(x, W, xb, Wb, head, s1, s2, hsum, nx4, nw4, N_);
  mega<<<gblocks + fblocks, 256, 0, stream>>>(xb, Wb, b, a, hb, s1, s2, hsum,
                                              edges, head, rec, N_, E_, mtiles, gblocks);
  row_softmax<<<N_, 128, 0, stream>>>(hb, s1, s2, head, rec, hsum, out, N_);
}